// Round 12
// baseline (178.750 us; speedup 1.0000x reference)
//
#include <hip/hip_runtime.h>
#include <math.h>

#define NBATCH 16
#define CH     32      // CHUNK
#define NP     20      // NPOINTS
#define LPTS   640     // CHUNK * NPOINTS
#define NT     256     // threads per block (4 waves); threads<128 own 3 points, else 2
#define DIMO   1024
#define TAB    1024    // LDS hash table slots (load factor 0.625)
#define GRID   2048    // one row per block; 8 blocks/CU -> 32 waves/CU

// Full-wave (64-lane) sum via DPP on the VALU pipe; result valid in lane 63 only.
__device__ __forceinline__ float wave_sum63(float v) {
    v += __int_as_float(__builtin_amdgcn_update_dpp(0, __float_as_int(v), 0x111, 0xF, 0xF, true)); // row_shr:1
    v += __int_as_float(__builtin_amdgcn_update_dpp(0, __float_as_int(v), 0x112, 0xF, 0xF, true)); // row_shr:2
    v += __int_as_float(__builtin_amdgcn_update_dpp(0, __float_as_int(v), 0x114, 0xF, 0xF, true)); // row_shr:4
    v += __int_as_float(__builtin_amdgcn_update_dpp(0, __float_as_int(v), 0x118, 0xF, 0xF, true)); // row_shr:8
    v += __int_as_float(__builtin_amdgcn_update_dpp(0, __float_as_int(v), 0x142, 0xA, 0xF, true)); // row_bcast:15 -> rows 1,3
    v += __int_as_float(__builtin_amdgcn_update_dpp(0, __float_as_int(v), 0x143, 0xC, 0xF, true)); // row_bcast:31 -> rows 2,3
    return v;
}

__global__ __launch_bounds__(NT, 8) void hyper_kernel(
    const float* __restrict__ input,     // (B, 1024)
    const float* __restrict__ res,       // (B, 4096, 4)
    const float* __restrict__ bias,      // (1024)
    const float* __restrict__ u_global,  // (B, 128, 32, 8, 2)
    const float* __restrict__ u_rel,     // (B, 128, 32, 8, 2)
    float* __restrict__ out)             // (B, 1024), zeroed by memset
{
    // cpar[c] = (A,B,C,D): prop = exp2(A*p2 + B*px + C*py + D)
    __shared__ float4 cpar[CH];
    __shared__ float cm0[CH], cm1[CH], cval[CH], colsum[CH];
    __shared__ __align__(16) float cscale[CH];
    // packed dedup table: (h << 11) | flat_point_idx ; EMPTY = ~0ULL
    __shared__ unsigned long long tab[TAB];
    float* const outacc = reinterpret_cast<float*>(tab);  // alias (tab dead after hash)

    const int tid = threadIdx.x;
    const bool has3 = (tid < LPTS - 2 * NT);   // 128 threads own a 3rd point

    const unsigned long long EMPTY = ~0ULL;
    const float L2E = 1.4426950408889634f;
    const float CEPS = (float)(1.0 - 1e-6);

    const int bk  = blockIdx.x;     // b*128 + k
    const int b   = bk >> 7;
    const int kk  = bk & 127;

    // --- init hash table + per-chunk params --------------------------------
    #pragma unroll
    for (int i = tid; i < TAB; i += NT) tab[i] = EMPTY;

    if (tid < CH) {
        colsum[tid] = 0.0f;
        const float* rp = res + (size_t)(bk * CH + tid) * 4;
        const float r0 = rp[0], r1 = rp[1], r2 = rp[2], r3 = rp[3];
        const float m0 = (1.0f / (1.0f + expf(-r0))) * 1023.0f;
        const float m1 = (1.0f / (1.0f + expf(-r1))) * 1023.0f;
        const float xx = r2 + 2.0f;
        const float sp = fmaxf(xx, 0.0f) + log1pf(expf(-fabsf(xx)));   // softplus
        const float sig = (sp + 1e-6f) * 1024.0f;
        const float isig = 1.0f / (1e-6f + sig);
        cm0[tid] = m0; cm1[tid] = m1;
        const float hA = -0.5f * L2E * isig;
        cpar[tid] = make_float4(hA, L2E * isig * m0, L2E * isig * m1,
                                hA * (m0 * m0 + m1 * m1));
        cval[tid] = r3;
    }
    __syncthreads();

    // --- build this thread's points (flat indices: tid, tid+NT, tid+2NT) ----
    int xs[3], ys[3];
    {
        const float2* ug = reinterpret_cast<const float2*>(u_global);
        const float2* ur = reinterpret_cast<const float2*>(u_rel);
        #pragma unroll
        for (int q = 0; q < 3; ++q) {
            if (q == 2 && !has3) break;
            const int fi = tid + q * NT;      // flat point index
            const int c  = fi / NP;
            const int p  = fi - c * NP;
            const float m0 = cm0[c], m1 = cm1[c];
            int x, y;
            if (p < 4) {
                x = (int)((p & 2) ? ceilf(m0) : floorf(m0));
                y = (int)((p & 1) ? ceilf(m1) : floorf(m1));
            } else if (p < 12) {
                const float2 u = ug[(bk * CH + c) * 8 + (p - 4)];
                x = (int)floorf((u.x * CEPS) * 1024.0f);
                y = (int)floorf((u.y * CEPS) * 1024.0f);
            } else {
                const float2 u = ur[(bk * CH + c) * 8 + (p - 12)];
                const float mn0 = rintf(m0), mn1 = rintf(m1);
                float lo0 = mn0 - 4.0f; if (lo0 < 0.0f) lo0 = 0.0f; if (mn0 + 4.0f > 1024.0f) lo0 = 1016.0f;
                float lo1 = mn1 - 4.0f; if (lo1 < 0.0f) lo1 = 0.0f; if (mn1 + 4.0f > 1024.0f) lo1 = 1016.0f;
                x = (int)floorf((u.x * CEPS) * 8.0f + lo0);
                y = (int)floorf((u.y * CEPS) * 8.0f + lo1);
            }
            xs[q] = x; ys[q] = y;
        }
    }

    // hoist input gathers
    const float in0 = input[b * DIMO + ys[0]];
    const float in1 = input[b * DIMO + ys[1]];
    const float in2 = has3 ? input[b * DIMO + ys[2]] : 0.0f;

    // --- duplicate detection: packed (h<<11 | idx), CAS-claim + atomicMin ---
    int hidx[3];
    #pragma unroll
    for (int q = 0; q < 3; ++q) {
        if (q == 2 && !has3) { hidx[2] = 0; break; }
        const int fi = tid + q * NT;
        const unsigned int a  = (unsigned int)((xs[q] + 1) * (xs[q] + 1));                    // <= 1025^2
        const unsigned int b3 = (unsigned int)((ys[q] + 1) * (ys[q] + 1) * (ys[q] + 1));      // < 2^31
        const unsigned long long h = (unsigned long long)a * b3;                              // < 2^51
        const unsigned long long pk = (h << 11) | (unsigned long long)fi;
        unsigned int hh = (unsigned int)(h ^ (h >> 31)) * 2654435761u;
        int idx = (int)(hh >> 22);            // 10 bits
        for (;;) {
            unsigned long long prev = atomicCAS(&tab[idx], EMPTY, pk);
            if (prev == EMPTY) break;
            if ((prev >> 11) == h) { atomicMin(&tab[idx], pk); break; }
            idx = (idx + 1) & (TAB - 1);
        }
        hidx[q] = idx;
    }
    __syncthreads();
    const float keep0 = ((int)(tab[hidx[0]] & 0x7FF) == tid)          ? 1.0f : 0.0f;
    const float keep1 = ((int)(tab[hidx[1]] & 0x7FF) == tid + NT)     ? 1.0f : 0.0f;
    const float keep2 = (has3 && (int)(tab[hidx[2]] & 0x7FF) == tid + 2 * NT) ? 1.0f : 0.0f;
    __syncthreads();   // everyone done reading tab before outacc overwrites it

    // tab is dead now: reuse as outacc; fold bias in for k==0 block
    #pragma unroll
    for (int i = tid; i < DIMO; i += NT) outacc[i] = (kk == 0) ? bias[i] : 0.0f;

    // --- pass 1: Gaussian props -> column sums (recompute in pass 2) --------
    const float px0 = (float)xs[0], py0 = (float)ys[0];
    const float px1 = (float)xs[1], py1 = (float)ys[1];
    const float px2 = (float)xs[2], py2 = (float)ys[2];
    const float p20 = px0 * px0 + py0 * py0;
    const float p21 = px1 * px1 + py1 * py1;
    const float p22 = px2 * px2 + py2 * py2;
    const bool lane63 = (tid & 63) == 63;

    #pragma unroll
    for (int j = 0; j < CH / 2; ++j) {
        const float4 cpA = cpar[2 * j];
        const float4 cpB = cpar[2 * j + 1];
        float sumA = __builtin_amdgcn_exp2f(fmaf(cpA.x, p20, fmaf(cpA.y, px0, fmaf(cpA.z, py0, cpA.w)))) * keep0
                   + __builtin_amdgcn_exp2f(fmaf(cpA.x, p21, fmaf(cpA.y, px1, fmaf(cpA.z, py1, cpA.w)))) * keep1;
        float sumB = __builtin_amdgcn_exp2f(fmaf(cpB.x, p20, fmaf(cpB.y, px0, fmaf(cpB.z, py0, cpB.w)))) * keep0
                   + __builtin_amdgcn_exp2f(fmaf(cpB.x, p21, fmaf(cpB.y, px1, fmaf(cpB.z, py1, cpB.w)))) * keep1;
        if (has3) {
            sumA += __builtin_amdgcn_exp2f(fmaf(cpA.x, p22, fmaf(cpA.y, px2, fmaf(cpA.z, py2, cpA.w)))) * keep2;
            sumB += __builtin_amdgcn_exp2f(fmaf(cpB.x, p22, fmaf(cpB.y, px2, fmaf(cpB.z, py2, cpB.w)))) * keep2;
        }
        const float sA = wave_sum63(sumA);
        const float sB = wave_sum63(sumB);
        if (lane63) {
            atomicAdd(&colsum[2 * j], sA);
            atomicAdd(&colsum[2 * j + 1], sB);
        }
    }
    __syncthreads();
    if (tid < CH) cscale[tid] = cval[tid] / colsum[tid];
    __syncthreads();

    // --- pass 2: recompute props, weighted sums (exact f32) -----------------
    float val0 = 0.0f, val1 = 0.0f, val2 = 0.0f;
    #pragma unroll
    for (int cc = 0; cc < CH; ++cc) {
        const float4 cp = cpar[cc];
        const float sc = cscale[cc];
        val0 = fmaf(__builtin_amdgcn_exp2f(fmaf(cp.x, p20, fmaf(cp.y, px0, fmaf(cp.z, py0, cp.w)))), sc, val0);
        val1 = fmaf(__builtin_amdgcn_exp2f(fmaf(cp.x, p21, fmaf(cp.y, px1, fmaf(cp.z, py1, cp.w)))), sc, val1);
        if (has3)
            val2 = fmaf(__builtin_amdgcn_exp2f(fmaf(cp.x, p22, fmaf(cp.y, px2, fmaf(cp.z, py2, cp.w)))), sc, val2);
    }
    val0 *= keep0;
    val1 *= keep1;
    val2 *= keep2;

    // --- stage scatter in LDS, flush coalesced ------------------------------
    atomicAdd(&outacc[xs[0]], val0 * in0);
    atomicAdd(&outacc[xs[1]], val1 * in1);
    if (has3) atomicAdd(&outacc[xs[2]], val2 * in2);
    __syncthreads();

    #pragma unroll
    for (int i = tid; i < DIMO; i += NT) {
        const float v = outacc[i];
        if (v != 0.0f) atomicAdd(&out[b * DIMO + i], v);
    }
}

extern "C" void kernel_launch(void* const* d_in, const int* in_sizes, int n_in,
                              void* d_out, int out_size, void* d_ws, size_t ws_size,
                              hipStream_t stream) {
    const float* input  = (const float*)d_in[0];
    const float* res    = (const float*)d_in[1];
    const float* bias   = (const float*)d_in[2];
    const float* u_glob = (const float*)d_in[3];
    const float* u_rel  = (const float*)d_in[4];
    // d_in[5] = temp_indices: dead in the reference (both columns overwritten)
    float* out = (float*)d_out;

    hipMemsetAsync(out, 0, (size_t)NBATCH * DIMO * sizeof(float), stream);
    hipLaunchKernelGGL(hyper_kernel, dim3(GRID), dim3(NT), 0, stream,
                       input, res, bias, u_glob, u_rel, out);
}

// Round 13
// 178.034 us; speedup vs baseline: 1.0040x; 1.0040x over previous
//
#include <hip/hip_runtime.h>
#include <math.h>

#define NBATCH 16
#define CH     32      // CHUNK
#define NP     20      // NPOINTS
#define LPTS   640     // CHUNK * NPOINTS
#define NT     256     // 4 waves; waves 0-1 (tid<128) own a 3rd point
#define DIMO   1024
#define TAB    1024    // LDS hash table slots (load factor 0.625)
#define GRID   2048    // one row per block; 8 blocks/CU -> 32 waves/CU

// Full-wave (64-lane) sum via DPP on the VALU pipe; result valid in lane 63 only.
__device__ __forceinline__ float wave_sum63(float v) {
    v += __int_as_float(__builtin_amdgcn_update_dpp(0, __float_as_int(v), 0x111, 0xF, 0xF, true)); // row_shr:1
    v += __int_as_float(__builtin_amdgcn_update_dpp(0, __float_as_int(v), 0x112, 0xF, 0xF, true)); // row_shr:2
    v += __int_as_float(__builtin_amdgcn_update_dpp(0, __float_as_int(v), 0x114, 0xF, 0xF, true)); // row_shr:4
    v += __int_as_float(__builtin_amdgcn_update_dpp(0, __float_as_int(v), 0x118, 0xF, 0xF, true)); // row_shr:8
    v += __int_as_float(__builtin_amdgcn_update_dpp(0, __float_as_int(v), 0x142, 0xA, 0xF, true)); // row_bcast:15 -> rows 1,3
    v += __int_as_float(__builtin_amdgcn_update_dpp(0, __float_as_int(v), 0x143, 0xC, 0xF, true)); // row_bcast:31 -> rows 2,3
    return v;
}

__device__ __forceinline__ void build_point(
    int fi, int bk, const float* cm0, const float* cm1,
    const float2* __restrict__ ug, const float2* __restrict__ ur,
    int& x, int& y)
{
    const float CEPS = (float)(1.0 - 1e-6);
    const int c = fi / NP;
    const int p = fi - c * NP;
    const float m0 = cm0[c], m1 = cm1[c];
    if (p < 4) {
        x = (int)((p & 2) ? ceilf(m0) : floorf(m0));
        y = (int)((p & 1) ? ceilf(m1) : floorf(m1));
    } else if (p < 12) {
        const float2 u = ug[(bk * CH + c) * 8 + (p - 4)];
        x = (int)floorf((u.x * CEPS) * 1024.0f);
        y = (int)floorf((u.y * CEPS) * 1024.0f);
    } else {
        const float2 u = ur[(bk * CH + c) * 8 + (p - 12)];
        const float mn0 = rintf(m0), mn1 = rintf(m1);
        float lo0 = mn0 - 4.0f; if (lo0 < 0.0f) lo0 = 0.0f; if (mn0 + 4.0f > 1024.0f) lo0 = 1016.0f;
        float lo1 = mn1 - 4.0f; if (lo1 < 0.0f) lo1 = 0.0f; if (mn1 + 4.0f > 1024.0f) lo1 = 1016.0f;
        x = (int)floorf((u.x * CEPS) * 8.0f + lo0);
        y = (int)floorf((u.y * CEPS) * 8.0f + lo1);
    }
}

__device__ __forceinline__ int probe_insert(unsigned long long* tab, int x, int y, int fi) {
    const unsigned int a  = (unsigned int)((x + 1) * (x + 1));               // <= 1025^2
    const unsigned int b3 = (unsigned int)((y + 1) * (y + 1) * (y + 1));     // <= 1025^3 < 2^31
    const unsigned long long h = (unsigned long long)a * b3;                 // < 2^51
    const unsigned long long pk = (h << 11) | (unsigned long long)fi;
    unsigned int hh = (unsigned int)(h ^ (h >> 31)) * 2654435761u;
    int idx = (int)(hh >> 22);            // 10 bits
    for (;;) {
        unsigned long long prev = atomicCAS(&tab[idx], ~0ULL, pk);
        if (prev == ~0ULL) break;                               // claimed with our idx
        if ((prev >> 11) == h) { atomicMin(&tab[idx], pk); break; }
        idx = (idx + 1) & (TAB - 1);
    }
    return idx;
}

__global__ __launch_bounds__(NT, 8) void hyper_kernel(
    const float* __restrict__ input,     // (B, 1024)
    const float* __restrict__ res,       // (B, 4096, 4)
    const float* __restrict__ bias,      // (1024)
    const float* __restrict__ u_global,  // (B, 128, 32, 8, 2)
    const float* __restrict__ u_rel,     // (B, 128, 32, 8, 2)
    float* __restrict__ out)             // (B, 1024), zeroed by memset
{
    // cpar[c] = (A,B,C,D): prop = exp2(A*p2 + B*px + C*py + D)
    __shared__ float4 cpar[CH];
    __shared__ float cm0[CH], cm1[CH], cval[CH], colsum[CH];
    __shared__ __align__(16) float cscale[CH];
    // packed dedup table: (h << 11) | flat_point_idx ; EMPTY = ~0ULL
    __shared__ unsigned long long tab[TAB];
    float* const outacc = reinterpret_cast<float*>(tab);  // alias (tab dead after hash)

    const int tid = threadIdx.x;
    const bool has3 = (tid < LPTS - 2 * NT);   // tid<128: waves 0-1, wave-uniform

    const float L2E = 1.4426950408889634f;

    const int bk  = blockIdx.x;     // b*128 + k
    const int b   = bk >> 7;
    const int kk  = bk & 127;

    // --- init hash table + per-chunk params --------------------------------
    #pragma unroll
    for (int i = tid; i < TAB; i += NT) tab[i] = ~0ULL;

    if (tid < CH) {
        colsum[tid] = 0.0f;
        const float* rp = res + (size_t)(bk * CH + tid) * 4;
        const float r0 = rp[0], r1 = rp[1], r2 = rp[2], r3 = rp[3];
        const float m0 = (1.0f / (1.0f + expf(-r0))) * 1023.0f;
        const float m1 = (1.0f / (1.0f + expf(-r1))) * 1023.0f;
        const float xx = r2 + 2.0f;
        const float sp = fmaxf(xx, 0.0f) + log1pf(expf(-fabsf(xx)));   // softplus
        const float sig = (sp + 1e-6f) * 1024.0f;
        const float isig = 1.0f / (1e-6f + sig);
        cm0[tid] = m0; cm1[tid] = m1;
        const float hA = -0.5f * L2E * isig;
        cpar[tid] = make_float4(hA, L2E * isig * m0, L2E * isig * m1,
                                hA * (m0 * m0 + m1 * m1));
        cval[tid] = r3;
    }
    __syncthreads();

    // --- build points (explicit scalars — no arrays, no runtime indexing) ---
    const float2* ug = reinterpret_cast<const float2*>(u_global);
    const float2* ur = reinterpret_cast<const float2*>(u_rel);
    int x0, y0, x1, y1, x2 = 0, y2 = 0;
    build_point(tid,          bk, cm0, cm1, ug, ur, x0, y0);
    build_point(tid + NT,     bk, cm0, cm1, ug, ur, x1, y1);
    if (has3) build_point(tid + 2 * NT, bk, cm0, cm1, ug, ur, x2, y2);

    // hoist input gathers (overlap global latency with hash phase)
    const float in0 = input[b * DIMO + y0];
    const float in1 = input[b * DIMO + y1];
    const float in2 = has3 ? input[b * DIMO + y2] : 0.0f;

    // --- duplicate detection ------------------------------------------------
    const int i0 = probe_insert(tab, x0, y0, tid);
    const int i1 = probe_insert(tab, x1, y1, tid + NT);
    const int i2 = has3 ? probe_insert(tab, x2, y2, tid + 2 * NT) : 0;
    __syncthreads();
    const float keep0 = ((int)(tab[i0] & 0x7FF) == tid)               ? 1.0f : 0.0f;
    const float keep1 = ((int)(tab[i1] & 0x7FF) == tid + NT)          ? 1.0f : 0.0f;
    const float keep2 = (has3 && (int)(tab[i2] & 0x7FF) == tid + 2 * NT) ? 1.0f : 0.0f;
    __syncthreads();   // all tab reads done before outacc overwrites it

    // tab is dead now: reuse as outacc; fold bias in for k==0 block
    #pragma unroll
    for (int i = tid; i < DIMO; i += NT) outacc[i] = (kk == 0) ? bias[i] : 0.0f;

    // --- pass 1: Gaussian props -> column sums (recompute in pass 2) --------
    const float px0 = (float)x0, py0 = (float)y0;
    const float px1 = (float)x1, py1 = (float)y1;
    const float px2 = (float)x2, py2 = (float)y2;
    const float p20 = px0 * px0 + py0 * py0;
    const float p21 = px1 * px1 + py1 * py1;
    const float p22 = px2 * px2 + py2 * py2;
    const bool lane63 = (tid & 63) == 63;

    #pragma unroll
    for (int j = 0; j < CH / 2; ++j) {
        const float4 cpA = cpar[2 * j];
        const float4 cpB = cpar[2 * j + 1];
        float sumA = __builtin_amdgcn_exp2f(fmaf(cpA.x, p20, fmaf(cpA.y, px0, fmaf(cpA.z, py0, cpA.w)))) * keep0
                   + __builtin_amdgcn_exp2f(fmaf(cpA.x, p21, fmaf(cpA.y, px1, fmaf(cpA.z, py1, cpA.w)))) * keep1;
        float sumB = __builtin_amdgcn_exp2f(fmaf(cpB.x, p20, fmaf(cpB.y, px0, fmaf(cpB.z, py0, cpB.w)))) * keep0
                   + __builtin_amdgcn_exp2f(fmaf(cpB.x, p21, fmaf(cpB.y, px1, fmaf(cpB.z, py1, cpB.w)))) * keep1;
        if (has3) {   // wave-uniform branch (tid<128)
            sumA = fmaf(__builtin_amdgcn_exp2f(fmaf(cpA.x, p22, fmaf(cpA.y, px2, fmaf(cpA.z, py2, cpA.w)))), keep2, sumA);
            sumB = fmaf(__builtin_amdgcn_exp2f(fmaf(cpB.x, p22, fmaf(cpB.y, px2, fmaf(cpB.z, py2, cpB.w)))), keep2, sumB);
        }
        const float sA = wave_sum63(sumA);
        const float sB = wave_sum63(sumB);
        if (lane63) {
            atomicAdd(&colsum[2 * j], sA);
            atomicAdd(&colsum[2 * j + 1], sB);
        }
    }
    __syncthreads();
    if (tid < CH) cscale[tid] = cval[tid] / colsum[tid];
    __syncthreads();

    // --- pass 2: recompute props, weighted sums (exact f32) -----------------
    float val0 = 0.0f, val1 = 0.0f, val2 = 0.0f;
    #pragma unroll
    for (int cc = 0; cc < CH; ++cc) {
        const float4 cp = cpar[cc];
        const float sc = cscale[cc];
        val0 = fmaf(__builtin_amdgcn_exp2f(fmaf(cp.x, p20, fmaf(cp.y, px0, fmaf(cp.z, py0, cp.w)))), sc, val0);
        val1 = fmaf(__builtin_amdgcn_exp2f(fmaf(cp.x, p21, fmaf(cp.y, px1, fmaf(cp.z, py1, cp.w)))), sc, val1);
        if (has3)
            val2 = fmaf(__builtin_amdgcn_exp2f(fmaf(cp.x, p22, fmaf(cp.y, px2, fmaf(cp.z, py2, cp.w)))), sc, val2);
    }
    val0 *= keep0;
    val1 *= keep1;
    val2 *= keep2;

    // --- stage scatter in LDS, flush coalesced ------------------------------
    atomicAdd(&outacc[x0], val0 * in0);
    atomicAdd(&outacc[x1], val1 * in1);
    if (has3) atomicAdd(&outacc[x2], val2 * in2);
    __syncthreads();

    #pragma unroll
    for (int i = tid; i < DIMO; i += NT) {
        const float v = outacc[i];
        if (v != 0.0f) atomicAdd(&out[b * DIMO + i], v);
    }
}

extern "C" void kernel_launch(void* const* d_in, const int* in_sizes, int n_in,
                              void* d_out, int out_size, void* d_ws, size_t ws_size,
                              hipStream_t stream) {
    const float* input  = (const float*)d_in[0];
    const float* res    = (const float*)d_in[1];
    const float* bias   = (const float*)d_in[2];
    const float* u_glob = (const float*)d_in[3];
    const float* u_rel  = (const float*)d_in[4];
    // d_in[5] = temp_indices: dead in the reference (both columns overwritten)
    float* out = (float*)d_out;

    hipMemsetAsync(out, 0, (size_t)NBATCH * DIMO * sizeof(float), stream);
    hipLaunchKernelGGL(hyper_kernel, dim3(GRID), dim3(NT), 0, stream,
                       input, res, bias, u_glob, u_rel, out);
}

// Round 15
// 142.984 us; speedup vs baseline: 1.2501x; 1.2451x over previous
//
#include <hip/hip_runtime.h>
#include <math.h>

#define NBATCH 16
#define CH     32      // CHUNK
#define NP     20      // NPOINTS
#define LPTS   640     // CHUNK * NPOINTS
#define NT     256     // 4 waves; waves 0-1 (tid<128) own a 3rd point
#define DIMO   1024
#define TAB    1024    // LDS hash table slots (load factor 0.625)
#define GRID   2048    // one row per block; 8 blocks/CU -> 32 waves/CU

// Full-wave (64-lane) sum via DPP on the VALU pipe; result valid in lane 63 only.
__device__ __forceinline__ float wave_sum63(float v) {
    v += __int_as_float(__builtin_amdgcn_update_dpp(0, __float_as_int(v), 0x111, 0xF, 0xF, true)); // row_shr:1
    v += __int_as_float(__builtin_amdgcn_update_dpp(0, __float_as_int(v), 0x112, 0xF, 0xF, true)); // row_shr:2
    v += __int_as_float(__builtin_amdgcn_update_dpp(0, __float_as_int(v), 0x114, 0xF, 0xF, true)); // row_shr:4
    v += __int_as_float(__builtin_amdgcn_update_dpp(0, __float_as_int(v), 0x118, 0xF, 0xF, true)); // row_shr:8
    v += __int_as_float(__builtin_amdgcn_update_dpp(0, __float_as_int(v), 0x142, 0xA, 0xF, true)); // row_bcast:15 -> rows 1,3
    v += __int_as_float(__builtin_amdgcn_update_dpp(0, __float_as_int(v), 0x143, 0xC, 0xF, true)); // row_bcast:31 -> rows 2,3
    return v;
}

__device__ __forceinline__ void build_point(
    int fi, int bk, const float* cm0, const float* cm1,
    const float2* __restrict__ ug, const float2* __restrict__ ur,
    int& x, int& y)
{
    const float CEPS = (float)(1.0 - 1e-6);
    const int c = fi / NP;
    const int p = fi - c * NP;
    const float m0 = cm0[c], m1 = cm1[c];
    if (p < 4) {
        x = (int)((p & 2) ? ceilf(m0) : floorf(m0));
        y = (int)((p & 1) ? ceilf(m1) : floorf(m1));
    } else if (p < 12) {
        const float2 u = ug[(bk * CH + c) * 8 + (p - 4)];
        x = (int)floorf((u.x * CEPS) * 1024.0f);
        y = (int)floorf((u.y * CEPS) * 1024.0f);
    } else {
        const float2 u = ur[(bk * CH + c) * 8 + (p - 12)];
        const float mn0 = rintf(m0), mn1 = rintf(m1);
        float lo0 = mn0 - 4.0f; if (lo0 < 0.0f) lo0 = 0.0f; if (mn0 + 4.0f > 1024.0f) lo0 = 1016.0f;
        float lo1 = mn1 - 4.0f; if (lo1 < 0.0f) lo1 = 0.0f; if (mn1 + 4.0f > 1024.0f) lo1 = 1016.0f;
        x = (int)floorf((u.x * CEPS) * 8.0f + lo0);
        y = (int)floorf((u.y * CEPS) * 8.0f + lo1);
    }
}

__device__ __forceinline__ int probe_insert(unsigned long long* tab, int x, int y, int fi) {
    const unsigned int a  = (unsigned int)((x + 1) * (x + 1));               // <= 1025^2
    const unsigned int b3 = (unsigned int)((y + 1) * (y + 1) * (y + 1));     // <= 1025^3 < 2^31
    const unsigned long long h = (unsigned long long)a * b3;                 // < 2^51
    const unsigned long long pk = (h << 11) | (unsigned long long)fi;
    unsigned int hh = (unsigned int)(h ^ (h >> 31)) * 2654435761u;
    int idx = (int)(hh >> 22);            // 10 bits
    for (;;) {
        unsigned long long prev = atomicCAS(&tab[idx], ~0ULL, pk);
        if (prev == ~0ULL) break;                               // claimed with our idx
        if ((prev >> 11) == h) { atomicMin(&tab[idx], pk); break; }
        idx = (idx + 1) & (TAB - 1);
    }
    return idx;
}

__global__ __launch_bounds__(NT, 4) void hyper_kernel(
    const float* __restrict__ input,     // (B, 1024)
    const float* __restrict__ res,       // (B, 4096, 4)
    const float* __restrict__ bias,      // (1024)
    const float* __restrict__ u_global,  // (B, 128, 32, 8, 2)
    const float* __restrict__ u_rel,     // (B, 128, 32, 8, 2)
    float* __restrict__ out)             // (B, 1024), zeroed by memset
{
    // cpar[c] = (A,B,C,D): prop = exp2(A*p2 + B*px + C*py + D)
    __shared__ float4 cpar[CH];
    __shared__ float cm0[CH], cm1[CH], cval[CH], colsum[CH];
    __shared__ __align__(16) float cscale[CH];
    // packed dedup table: (h << 11) | flat_point_idx ; EMPTY = ~0ULL
    __shared__ unsigned long long tab[TAB];
    float* const outacc = reinterpret_cast<float*>(tab);  // alias (tab dead after hash)

    const int tid = threadIdx.x;
    const bool has3 = (tid < LPTS - 2 * NT);   // tid<128: waves 0-1, wave-uniform

    const float L2E = 1.4426950408889634f;

    const int bk  = blockIdx.x;     // b*128 + k
    const int b   = bk >> 7;
    const int kk  = bk & 127;

    // --- init hash table + per-chunk params --------------------------------
    for (int i = tid; i < TAB; i += NT) tab[i] = ~0ULL;

    if (tid < CH) {
        colsum[tid] = 0.0f;
        const float* rp = res + (size_t)(bk * CH + tid) * 4;
        const float r0 = rp[0], r1 = rp[1], r2 = rp[2], r3 = rp[3];
        const float m0 = (1.0f / (1.0f + expf(-r0))) * 1023.0f;
        const float m1 = (1.0f / (1.0f + expf(-r1))) * 1023.0f;
        const float xx = r2 + 2.0f;
        const float sp = fmaxf(xx, 0.0f) + log1pf(expf(-fabsf(xx)));   // softplus
        const float sig = (sp + 1e-6f) * 1024.0f;
        const float isig = 1.0f / (1e-6f + sig);
        cm0[tid] = m0; cm1[tid] = m1;
        const float hA = -0.5f * L2E * isig;
        cpar[tid] = make_float4(hA, L2E * isig * m0, L2E * isig * m1,
                                hA * (m0 * m0 + m1 * m1));
        cval[tid] = r3;
    }
    __syncthreads();

    // --- build points (explicit scalars — no arrays, no runtime indexing) ---
    const float2* ug = reinterpret_cast<const float2*>(u_global);
    const float2* ur = reinterpret_cast<const float2*>(u_rel);
    int x0, y0, x1, y1, x2 = 0, y2 = 0;
    build_point(tid,          bk, cm0, cm1, ug, ur, x0, y0);
    build_point(tid + NT,     bk, cm0, cm1, ug, ur, x1, y1);
    if (has3) build_point(tid + 2 * NT, bk, cm0, cm1, ug, ur, x2, y2);

    // hoist input gathers (overlap global latency with hash phase)
    const float in0 = input[b * DIMO + y0];
    const float in1 = input[b * DIMO + y1];
    const float in2 = has3 ? input[b * DIMO + y2] : 0.0f;

    // --- duplicate detection ------------------------------------------------
    const int i0 = probe_insert(tab, x0, y0, tid);
    const int i1 = probe_insert(tab, x1, y1, tid + NT);
    const int i2 = has3 ? probe_insert(tab, x2, y2, tid + 2 * NT) : 0;
    __syncthreads();
    const float keep0 = ((int)(tab[i0] & 0x7FF) == tid)               ? 1.0f : 0.0f;
    const float keep1 = ((int)(tab[i1] & 0x7FF) == tid + NT)          ? 1.0f : 0.0f;
    const float keep2 = (has3 && (int)(tab[i2] & 0x7FF) == tid + 2 * NT) ? 1.0f : 0.0f;
    __syncthreads();   // all tab reads done before outacc overwrites it

    // tab is dead now: reuse as outacc; fold bias in for k==0 block
    for (int i = tid; i < DIMO; i += NT) outacc[i] = (kk == 0) ? bias[i] : 0.0f;

    // --- pass 1: Gaussian props -> column sums (recompute in pass 2) --------
    const float px0 = (float)x0, py0 = (float)y0;
    const float px1 = (float)x1, py1 = (float)y1;
    const float px2 = (float)x2, py2 = (float)y2;
    const float p20 = px0 * px0 + py0 * py0;
    const float p21 = px1 * px1 + py1 * py1;
    const float p22 = px2 * px2 + py2 * py2;
    const bool lane63 = (tid & 63) == 63;

    #pragma unroll
    for (int j = 0; j < CH / 2; ++j) {
        const float4 cpA = cpar[2 * j];
        const float4 cpB = cpar[2 * j + 1];
        float sumA = __builtin_amdgcn_exp2f(fmaf(cpA.x, p20, fmaf(cpA.y, px0, fmaf(cpA.z, py0, cpA.w)))) * keep0
                   + __builtin_amdgcn_exp2f(fmaf(cpA.x, p21, fmaf(cpA.y, px1, fmaf(cpA.z, py1, cpA.w)))) * keep1;
        float sumB = __builtin_amdgcn_exp2f(fmaf(cpB.x, p20, fmaf(cpB.y, px0, fmaf(cpB.z, py0, cpB.w)))) * keep0
                   + __builtin_amdgcn_exp2f(fmaf(cpB.x, p21, fmaf(cpB.y, px1, fmaf(cpB.z, py1, cpB.w)))) * keep1;
        if (has3) {   // wave-uniform branch (tid<128)
            sumA = fmaf(__builtin_amdgcn_exp2f(fmaf(cpA.x, p22, fmaf(cpA.y, px2, fmaf(cpA.z, py2, cpA.w)))), keep2, sumA);
            sumB = fmaf(__builtin_amdgcn_exp2f(fmaf(cpB.x, p22, fmaf(cpB.y, px2, fmaf(cpB.z, py2, cpB.w)))), keep2, sumB);
        }
        const float sA = wave_sum63(sumA);
        const float sB = wave_sum63(sumB);
        if (lane63) {
            atomicAdd(&colsum[2 * j], sA);
            atomicAdd(&colsum[2 * j + 1], sB);
        }
    }
    __syncthreads();
    if (tid < CH) cscale[tid] = cval[tid] / colsum[tid];
    __syncthreads();

    // --- pass 2: recompute props, weighted sums (exact f32) -----------------
    float val0 = 0.0f, val1 = 0.0f, val2 = 0.0f;
    #pragma unroll
    for (int cc = 0; cc < CH; ++cc) {
        const float4 cp = cpar[cc];
        const float sc = cscale[cc];
        val0 = fmaf(__builtin_amdgcn_exp2f(fmaf(cp.x, p20, fmaf(cp.y, px0, fmaf(cp.z, py0, cp.w)))), sc, val0);
        val1 = fmaf(__builtin_amdgcn_exp2f(fmaf(cp.x, p21, fmaf(cp.y, px1, fmaf(cp.z, py1, cp.w)))), sc, val1);
        if (has3)
            val2 = fmaf(__builtin_amdgcn_exp2f(fmaf(cp.x, p22, fmaf(cp.y, px2, fmaf(cp.z, py2, cp.w)))), sc, val2);
    }
    val0 *= keep0;
    val1 *= keep1;
    val2 *= keep2;

    // --- stage scatter in LDS, flush coalesced ------------------------------
    atomicAdd(&outacc[x0], val0 * in0);
    atomicAdd(&outacc[x1], val1 * in1);
    if (has3) atomicAdd(&outacc[x2], val2 * in2);
    __syncthreads();

    for (int i = tid; i < DIMO; i += NT) {
        const float v = outacc[i];
        if (v != 0.0f) atomicAdd(&out[b * DIMO + i], v);
    }
}

extern "C" void kernel_launch(void* const* d_in, const int* in_sizes, int n_in,
                              void* d_out, int out_size, void* d_ws, size_t ws_size,
                              hipStream_t stream) {
    const float* input  = (const float*)d_in[0];
    const float* res    = (const float*)d_in[1];
    const float* bias   = (const float*)d_in[2];
    const float* u_glob = (const float*)d_in[3];
    const float* u_rel  = (const float*)d_in[4];
    // d_in[5] = temp_indices: dead in the reference (both columns overwritten)
    float* out = (float*)d_out;

    hipMemsetAsync(out, 0, (size_t)NBATCH * DIMO * sizeof(float), stream);
    hipLaunchKernelGGL(hyper_kernel, dim3(GRID), dim3(NT), 0, stream,
                       input, res, bias, u_glob, u_rel, out);
}